// Round 12
// baseline (280.730 us; speedup 1.0000x reference)
//
#include <hip/hip_runtime.h>

#define DIM 512

// sign = (-1)^par as a float, branchless
__device__ __forceinline__ float sgnf(int par) {
    return __int_as_float(0x3F800000u | ((unsigned)par << 31));
}

// ds_swizzle lane-xor: pattern = (xor<<10) | 0x1F   (only used once, in reduce)
template<int PAT>
__device__ __forceinline__ float swz(float x) {
    return __int_as_float(__builtin_amdgcn_ds_swizzle(__float_as_int(x), PAT));
}
// DPP move (VALU pipe): quad_perm 0xB1 = lane^1, 0x4E = lane^2, 0x128 = row_ror:8 = lane^8 (16-lane rows)
template<int CTRL>
__device__ __forceinline__ float dppmov(float x) {
    return __int_as_float(__builtin_amdgcn_mov_dpp(__float_as_int(x), CTRL, 0xF, 0xF, true));
}

// Layout: 4 states per wave; 16-lane group per state; lane holds 32 complex amps.
// idx = (g<<5)|j,  g = lane&15 (idx bits 5..8), j = register index (idx bits 0..4).
// E = (1/512) * sum_idx s[idx] * Re( conj(z[idx]) * z[idx^0x82] ), z = WHT(D1*psi).
// bit7 WHT stage + readout shuffle eliminated analytically:
//   z(b7=0)=v0+v1, z(b7=1)=v0-v1  =>  paired sum = 2s*[conj(v0)v0' - conj(v1)v1'] (lane-local).
__global__ __launch_bounds__(256) void qcnn9_kernel(
    const float* __restrict__ sr, const float* __restrict__ si,
    float* __restrict__ out, int bsz)
{
    const int wid   = (blockIdx.x * blockDim.x + threadIdx.x) >> 6;
    const int lane  = threadIdx.x & 63;
    const int g     = lane & 15;
    const int sIdx  = wid * 4 + (lane >> 4);
    const int state = min(sIdx, bsz - 1);     // clamp (grid tail safety)

    const float* __restrict__ pr = sr + (size_t)state * DIM + g * 32;
    const float* __restrict__ pi = si + (size_t)state * DIM + g * 32;

    // 32 consecutive floats per lane per array: 8+8 float4 loads
    float vr[32], vi[32];
    #pragma unroll
    for (int q = 0; q < 8; ++q) {
        float4 a = reinterpret_cast<const float4*>(pr)[q];
        vr[4*q] = a.x; vr[4*q+1] = a.y; vr[4*q+2] = a.z; vr[4*q+3] = a.w;
    }
    #pragma unroll
    for (int q = 0; q < 8; ++q) {
        float4 a = reinterpret_cast<const float4*>(pi)[q];
        vi[4*q] = a.x; vi[4*q+1] = a.y; vi[4*q+2] = a.z; vi[4*q+3] = a.w;
    }

    const int g0 = g & 1, g1 = (g >> 1) & 1, g2 = (g >> 2) & 1, g3 = (g >> 3) & 1;

    // D1 diagonal parity = A(j) ^ B(g) ^ (j4 & C(g))  [verified vs validated popc formula]
    // A(j) over {j0j1,j1j2,j2j3,j3j4,j1j4} -> maskA = 0x8B84B848
    // B(g) = g0g1 ^ g1g2 ^ g2g3 ;  C(g) = g0 ^ g2 (j4=1 <=> j>=16)
    {
        const int B = (g0 & g1) ^ (g1 & g2) ^ (g2 & g3);
        const int C = g0 ^ g2;
        unsigned M = 0x8B84B848u ^ (C ? 0xFFFF0000u : 0u) ^ (B ? 0xFFFFFFFFu : 0u);
        #pragma unroll
        for (int j = 0; j < 32; ++j) {
            float s = sgnf((M >> j) & 1);
            vr[j] *= s; vi[j] *= s;
        }
    }

    // WHT: 5 register-local stages (idx bits 0..4)
    #pragma unroll
    for (int b = 0; b < 5; ++b) {
        const int m = 1 << b;
        #pragma unroll
        for (int j = 0; j < 32; ++j) {
            if (!(j & m)) {
                const int k = j | m;
                float x, y;
                x = vr[j]; y = vr[k]; vr[j] = x + y; vr[k] = x - y;
                x = vi[j]; y = vi[k]; vi[j] = x + y; vi[k] = x - y;
            }
        }
    }

    // WHT cross-lane stages: idx bits 5,6,8 -> lane-xor 1,2,8 (ALL DPP / VALU pipe).
    // Bit 7 (lane-xor 4) stage intentionally SKIPPED (eliminated analytically).
#define XSTAGE(MBIT, CTRL)                                                    \
    {                                                                         \
        const float s_ = (lane & (MBIT)) ? -1.0f : 1.0f;                      \
        _Pragma("unroll")                                                     \
        for (int j = 0; j < 32; ++j) {                                        \
            float tr = dppmov<CTRL>(vr[j]);                                   \
            float ti = dppmov<CTRL>(vi[j]);                                   \
            vr[j] = fmaf(s_, vr[j], tr);                                      \
            vi[j] = fmaf(s_, vi[j], ti);                                      \
        }                                                                     \
    }
    XSTAGE(1, 0xB1)    // quad_perm [1,0,3,2]  = lane^1
    XSTAGE(2, 0x4E)    // quad_perm [2,3,0,1]  = lane^2
    XSTAGE(8, 0x128)   // row_ror:8            = lane^8 within 16-lane row
#undef XSTAGE

    // Readout (lane-local): sgn(j,g) from s[idx] = j4^j2^(j0&j2) ^ g1&~g3 ; v1-lanes (g2=1) negate.
    // maskSA = 0xAFAF5050. Partner j^2 is register-local (idx bit1).
    float acc = 0.0f;
    {
        const int SB = (g1 & (g3 ^ 1)) ^ g2;
        unsigned R = 0xAFAF5050u ^ (SB ? 0xFFFFFFFFu : 0u);
        #pragma unroll
        for (int j = 0; j < 32; ++j) {
            float p = fmaf(vr[j], vr[j ^ 2], vi[j] * vi[j ^ 2]);
            acc = fmaf(sgnf((R >> j) & 1), p, acc);
        }
    }

    // Reduce across the 16-lane group (3 DPP + 1 swizzle = the only DS op in the kernel)
    acc += dppmov<0xB1>(acc);     // lane^1
    acc += dppmov<0x4E>(acc);     // lane^2
    acc += swz<0x101F>(acc);      // lane^4
    acc += dppmov<0x128>(acc);    // lane^8

    // factor 2 (b7-pair) / 512  =  1/256
    if (g == 0 && sIdx < bsz) out[sIdx] = acc * (1.0f / 256.0f);
}

extern "C" void kernel_launch(void* const* d_in, const int* in_sizes, int n_in,
                              void* d_out, int out_size, void* d_ws, size_t ws_size,
                              hipStream_t stream) {
    const float* sr = (const float*)d_in[0];
    const float* si = (const float*)d_in[1];
    // d_in[2] = n_shots (<=0 -> analytical path) : unused
    float* out = (float*)d_out;
    const int bsz = in_sizes[0] / DIM;

    const int threads = 256;                        // 4 waves / block
    const int nwaves  = (bsz + 3) / 4;              // 4 states per wave
    const int blocks  = (nwaves * 64 + threads - 1) / threads;
    qcnn9_kernel<<<blocks, threads, 0, stream>>>(sr, si, out, bsz);
}